// Round 3
// baseline (563.018 us; speedup 1.0000x reference)
//
#include <hip/hip_runtime.h>

#define MNK (128*128*128)

// ---- in-wave sum on VALU/SALU pipes (no LDS traffic) ----
__device__ __forceinline__ float dpp_row_sum(float v) {
  int x;
  x = __builtin_amdgcn_update_dpp(0, __float_as_int(v), 0xB1, 0xF, 0xF, true);  // quad_perm xor1
  v += __int_as_float(x);
  x = __builtin_amdgcn_update_dpp(0, __float_as_int(v), 0x4E, 0xF, 0xF, true);  // quad_perm xor2
  v += __int_as_float(x);
  x = __builtin_amdgcn_update_dpp(0, __float_as_int(v), 0x141, 0xF, 0xF, true); // row_half_mirror
  v += __int_as_float(x);
  x = __builtin_amdgcn_update_dpp(0, __float_as_int(v), 0x140, 0xF, 0xF, true); // row_mirror
  v += __int_as_float(x);
  return v;  // uniform within each row of 16
}
__device__ __forceinline__ float wave_sum_all(float v) {
  v = dpp_row_sum(v);
  float s0 = __int_as_float(__builtin_amdgcn_readlane(__float_as_int(v), 0));
  float s1 = __int_as_float(__builtin_amdgcn_readlane(__float_as_int(v), 16));
  float s2 = __int_as_float(__builtin_amdgcn_readlane(__float_as_int(v), 32));
  float s3 = __int_as_float(__builtin_amdgcn_readlane(__float_as_int(v), 48));
  return (s0 + s1) + (s2 + s3);  // wave-uniform
}

// One workgroup per 8^3 spatial block (4096 blocks), 256 threads.
// Thread t -> p = t>>5, q = (t>>2)&7, r0 = 2*(t&3): (1,1,2) micro-tile.
// ALL 4 batches fused into one iteration loop: weights loaded once, 4x ILP,
// barriers amortized 4x. Reductions on VALU (DPP), not the DS pipe.
__global__ __launch_bounds__(256, 2) void gridnet_kernel(
    const float* __restrict__ weight, const float* __restrict__ bias,
    const float* __restrict__ rscale, const float* __restrict__ x,
    float* __restrict__ out) {
  __shared__ __align__(16) float Wl[4][1200];  // [batch][(wp*10+wq)*12 + wk]
  __shared__ __align__(16) float red[64];
  __shared__ __align__(16) float red2[8];

  const int t = threadIdx.x;
  const int r0 = (t & 3) * 2;
  const int q = (t >> 2) & 7;
  const int p = t >> 5;
  const int wv = t >> 6;
  const int lane = t & 63;

  // XCD swizzle: k-adjacent blocks share an XCD's L2
  const int H = blockIdx.x;
  const int L = (H & 7) * 512 + (H >> 3);
  const int bm = L >> 8, bn = (L >> 4) & 15, bk = L & 15;
  const int gm0 = bm * 8, gn0 = bn * 8, gk0 = bk * 8;
  const int baseg = ((gm0 + p) * 128 + (gn0 + q)) * 128 + (gk0 + r0);

  // ---- weights: 27 per output (k=r0 -> wA, k=r0+1 -> wB) ----
  float wA[27], wB[27];
  float SA = 0.f, SB = 0.f;
#pragma unroll
  for (int o = 0; o < 27; ++o) {
    float2 wvv = *(const float2*)(weight + o * MNK + baseg);
    wA[o] = wvv.x; wB[o] = wvv.y;
    SA += wvv.x; SB += wvv.y;
  }
  const float2 bv = *(const float2*)(bias + baseg);
  const float2 rv = *(const float2*)(rscale + baseg);

  // ---- load 10^3 windows for all 4 batches; fold halo stats once ----
  float sA[4] = {0, 0, 0, 0}, sQ[4] = {0, 0, 0, 0};
  float sH[4] = {0, 0, 0, 0}, sHq[4] = {0, 0, 0, 0};
  for (int idx = t; idx < 1000; idx += 256) {
    int wp = idx / 100;
    int rem = idx - wp * 100;
    int wq = rem / 10;
    int wk = rem - wq * 10;
    int gm = gm0 - 1 + wp, gn = gn0 - 1 + wq, gk = gk0 - 1 + wk;
    const bool inb = ((unsigned)gm < 128u && (unsigned)gn < 128u && (unsigned)gk < 128u);
    const int goff = (gm * 128 + gn) * 128 + gk;
    const int ai = (wp * 10 + wq) * 12 + wk;
    const bool shell = (wp == 0 || wp == 9 || wq == 0 || wq == 9 || wk == 0 || wk == 9);
#pragma unroll
    for (int b = 0; b < 4; ++b) {
      float v = inb ? x[b * MNK + goff] : 0.f;
      Wl[b][ai] = v;
      sA[b] += v; sQ[b] += v * v;
      if (shell) { sH[b] += v; sHq[b] += v * v; }
    }
  }
  // per-wave -> block sums (one-time)
  float P16[16];
#pragma unroll
  for (int b = 0; b < 4; ++b) {
    P16[b * 4 + 0] = wave_sum_all(sA[b]);
    P16[b * 4 + 1] = wave_sum_all(sQ[b]);
    P16[b * 4 + 2] = wave_sum_all(sH[b]);
    P16[b * 4 + 3] = wave_sum_all(sHq[b]);
  }
  if (lane == 0) {
    *(float4*)&red[wv * 16 + 0] = make_float4(P16[0], P16[1], P16[2], P16[3]);
    *(float4*)&red[wv * 16 + 4] = make_float4(P16[4], P16[5], P16[6], P16[7]);
    *(float4*)&red[wv * 16 + 8] = make_float4(P16[8], P16[9], P16[10], P16[11]);
    *(float4*)&red[wv * 16 + 12] = make_float4(P16[12], P16[13], P16[14], P16[15]);
  }
  __syncthreads();
  float tot[16];
#pragma unroll
  for (int j = 0; j < 16; ++j)
    tot[j] = red[j] + red[16 + j] + red[32 + j] + red[48 + j];

  float hS[4], hQ[4], mu[4], inv[4];
  float a[4][2];
  const int wi = ((p + 1) * 10 + q + 1) * 12 + r0 + 1;
#pragma unroll
  for (int b = 0; b < 4; ++b) {
    hS[b] = tot[b * 4 + 2]; hQ[b] = tot[b * 4 + 3];
    mu[b] = tot[b * 4 + 0] * 1e-3f;
    float var = tot[b * 4 + 1] * 1e-3f - mu[b] * mu[b];
    inv[b] = __builtin_amdgcn_rsqf(var + 1e-5f);
    a[b][0] = Wl[b][wi];
    a[b][1] = Wl[b][wi + 1];
  }

#pragma unroll 1
  for (int it = 0; it < 8; ++it) {
    float ls[4], lq[4];
#pragma unroll
    for (int b = 0; b < 4; ++b) {
      // 3^3 locally-connected conv on RAW acts (layernorm folded)
      float acc0 = 0.f, acc1 = 0.f;
#pragma unroll
      for (int i = 0; i < 3; ++i)
#pragma unroll
        for (int j = 0; j < 3; ++j) {
          const float* bp = &Wl[b][((p + i) * 10 + (q + j)) * 12 + r0];
          float2 u0 = *(const float2*)bp;
          float2 u1 = *(const float2*)(bp + 2);
          const int ob = i * 9 + j * 3;
          acc0 += wA[ob] * u0.x + wA[ob + 1] * u0.y + wA[ob + 2] * u1.x;
          acc1 += wB[ob] * u0.y + wB[ob + 1] * u1.x + wB[ob + 2] * u1.y;
        }
      const float im = inv[b] * mu[b];
      const float z0 = bv.x + inv[b] * acc0 - im * SA;
      const float z1 = bv.y + inv[b] * acc1 - im * SB;
      const float sg0 = __builtin_amdgcn_rcpf(1.f + __expf(-z0));
      const float sg1 = __builtin_amdgcn_rcpf(1.f + __expf(-z1));
      a[b][0] += rv.x * (z0 * sg0);
      a[b][1] += rv.y * (z1 * sg1);
      ls[b] = a[b][0] + a[b][1];
      lq[b] = a[b][0] * a[b][0] + a[b][1] * a[b][1];
    }
    if (it < 7) {
      float P[8];
#pragma unroll
      for (int b = 0; b < 4; ++b) {
        P[b * 2 + 0] = wave_sum_all(ls[b]);
        P[b * 2 + 1] = wave_sum_all(lq[b]);
      }
      if (lane == 0) {
        *(float4*)&red[wv * 8 + 0] = make_float4(P[0], P[1], P[2], P[3]);
        *(float4*)&red[wv * 8 + 4] = make_float4(P[4], P[5], P[6], P[7]);
      }
      __syncthreads();  // A: all conv reads done; red partials visible
#pragma unroll
      for (int b = 0; b < 4; ++b) {
        Wl[b][wi] = a[b][0];
        Wl[b][wi + 1] = a[b][1];
      }
      if (t < 32) {  // combine 4 wave-partials per quantity (8 quantities)
        float v = red[t];
        v += __int_as_float(__builtin_amdgcn_ds_swizzle(__float_as_int(v), 0x201F)); // xor8
        v += __int_as_float(__builtin_amdgcn_ds_swizzle(__float_as_int(v), 0x401F)); // xor16
        if (t < 8) red2[t] = v;
      }
      __syncthreads();  // B: interior writes + red2 visible
      float4 c0 = *(float4*)&red2[0];
      float4 c1 = *(float4*)&red2[4];
      const float S8[8] = {c0.x, c0.y, c0.z, c0.w, c1.x, c1.y, c1.z, c1.w};
#pragma unroll
      for (int b = 0; b < 4; ++b) {
        const float tS = S8[b * 2 + 0] + hS[b];
        const float tQ = S8[b * 2 + 1] + hQ[b];
        mu[b] = tS * 1e-3f;
        float var = tQ * 1e-3f - mu[b] * mu[b];
        inv[b] = __builtin_amdgcn_rsqf(var + 1e-5f);
      }
    }
  }

  // ---- write final interiors ----
#pragma unroll
  for (int b = 0; b < 4; ++b) {
    const int baseo = ((b * 128 + gm0 + p) * 128 + (gn0 + q)) * 128 + (gk0 + r0);
    float2 ov; ov.x = a[b][0]; ov.y = a[b][1];
    *(float2*)(out + baseo) = ov;
  }
}

extern "C" void kernel_launch(void* const* d_in, const int* in_sizes, int n_in,
                              void* d_out, int out_size, void* d_ws, size_t ws_size,
                              hipStream_t stream) {
  const float* weight = (const float*)d_in[0];
  const float* bias   = (const float*)d_in[1];
  const float* rscale = (const float*)d_in[2];
  const float* x      = (const float*)d_in[3];
  float* out = (float*)d_out;
  gridnet_kernel<<<dim3(16 * 16 * 16), dim3(256), 0, stream>>>(
      weight, bias, rscale, x, out);
}